// Round 13
// baseline (263.679 us; speedup 1.0000x reference)
//
#include <hip/hip_runtime.h>
#include <hip/hip_bf16.h>
#include <math.h>

// HMM forward (logZ), K=64 tags, V=50000, D=128, BATCH=8192, L=126.
// Transposed MFMA recurrence: beta_next = (T'^T x beta) .* e; C-layout ->
// next-B-layout transform by in-lane register renaming. Producer-consumer
// wave specialization; fp8 e4m3 emission table (3.2 MB, fits per-XCD L2),
// permuted rows, 1 global_load_lds per step.
// r13: (a) k_sumA folded into k_emit via last-block atomic (one launch less);
// (b) consumer K-tiles computed as INDEPENDENT MFMAs + VALU add — removes
// one dependent MFMA from the 126-step critical chain.
//
// ws layout:
//   [0, 3,200,000)        btn8[v][64]   fp8e4m3  raw exp(logit), permuted order
//   [3,200,000, +16384)   A[i][j]       f32      softmax(WA, col BOS=-inf)+EPS
//   [3,216,384, +256)     sumexp[k]     f32
//   [3,216,640, +200704)  partial[k][784] f32    per-block column sums
//   [3,417,344, +4)       counter       u32      k_emit arrival counter

#define KT 64
#define VV 50000
#define DD 128
#define BOS_T 62
#define EOS_T 63
#define LLEN 126
#define EPSF 1e-45f
#define SCALE_F 65536.0f
#define LOG_TOTAL_SCALE (2016.0f * 0.6931471805599453f)
#define NBLK 782          // k_emit grid
#define PBLK 784          // padded partial row
#define TPH 21            // k_fwd steps per phase (126 = 6*21)
#define NPH 6

#define BTN_OFF   0
#define A_OFF     3200000
#define SUM_OFF   3216384
#define PART_OFF  3216640
#define CNT_OFF   3417344

typedef short short8 __attribute__((ext_vector_type(8)));
typedef float f32x4  __attribute__((ext_vector_type(4)));
typedef float f32x2  __attribute__((ext_vector_type(2)));

union U8 { short8 v; unsigned u[4]; short s[8]; };

static __device__ inline unsigned short f2bf_u(float x) {
    __hip_bfloat16 h = __float2bfloat16(x);
    return *reinterpret_cast<unsigned short*>(&h);
}
static __device__ inline short f2bf(float x) { return (short)f2bf_u(x); }

#if __has_builtin(__builtin_amdgcn_cvt_pk_bf16_f32)
typedef __bf16 bf16x2 __attribute__((ext_vector_type(2)));
static __device__ inline unsigned pk2(float a, float b) {
    bf16x2 r = __builtin_amdgcn_cvt_pk_bf16_f32(a, b);
    return *reinterpret_cast<unsigned*>(&r);
}
#else
static __device__ inline unsigned pk2(float a, float b) {
    union { float f; unsigned u; } ua, ub;
    ua.f = a; ub.f = b;
    return ((ua.u + 0x8000u) >> 16) | ((ub.u + 0x8000u) & 0xFFFF0000u);
}
#endif

// ---- fp8 e4m3fn pack/unpack (values here are positive normals in [0.7,1.5])
#if __has_builtin(__builtin_amdgcn_cvt_pk_fp8_f32)
static __device__ inline unsigned pk4f8(float a, float b, float c, float d) {
    int v = __builtin_amdgcn_cvt_pk_fp8_f32(a, b, 0, false);
    v = __builtin_amdgcn_cvt_pk_fp8_f32(c, d, v, true);
    return (unsigned)v;
}
#else
static __device__ inline unsigned enc1f8(float x) {
    union { float f; unsigned u; } c; c.f = x;
    unsigned u = c.u & 0x7FFFFFFFu;
    unsigned r = u + 0x7FFFFu + ((u >> 20) & 1u);   // RNE to 3 mantissa bits
    return ((r >> 20) - (120u << 3)) & 0x7Fu;       // rebias 127->7
}
static __device__ inline unsigned pk4f8(float a, float b, float c, float d) {
    return enc1f8(a) | (enc1f8(b) << 8) | (enc1f8(c) << 16) | (enc1f8(d) << 24);
}
#endif

#if __has_builtin(__builtin_amdgcn_cvt_pk_f32_fp8)
static __device__ inline f32x2 dec2lo(unsigned w) { return __builtin_amdgcn_cvt_pk_f32_fp8((int)w, false); }
static __device__ inline f32x2 dec2hi(unsigned w) { return __builtin_amdgcn_cvt_pk_f32_fp8((int)w, true); }
#else
static __device__ inline float dec1f8(unsigned b) {
    union { unsigned u; float f; } c;
    c.u = ((b & 0x80u) << 24) | (((b & 0x7Fu) << 20) + (120u << 23));
    return c.f;
}
static __device__ inline f32x2 dec2lo(unsigned w) { f32x2 r; r.x = dec1f8(w & 0xFF); r.y = dec1f8((w >> 8) & 0xFF); return r; }
static __device__ inline f32x2 dec2hi(unsigned w) { f32x2 r; r.x = dec1f8((w >> 16) & 0xFF); r.y = dec1f8(w >> 24); return r; }
#endif

// async global(per-lane addr) -> LDS(uniform base + lane*16B), 16 B/lane
#if __has_builtin(__builtin_amdgcn_global_load_lds)
#define GLLDS(gp, lbase)                                                        \
    __builtin_amdgcn_global_load_lds(                                           \
        (__attribute__((address_space(1))) void*)const_cast<unsigned char*>(gp),\
        (__attribute__((address_space(3))) void*)(lbase), 16, 0, 0)
#else
#define GLLDS(gp, lbase)                                                        \
    do { *(uint4*)((unsigned char*)(lbase) + (threadIdx.x & 63) * 16) =         \
             *(const uint4*)(gp); } while (0)
#endif

// ---------------------------------------------------------------- btn8[v][pos(k)] = fp8(exp(ThetaB[k].E[v]))  (MFMA GEMM)
// Last-arriving block also reduces partial->sumexp and computes A=softmax(WA)
// (folds the former k_sumA launch).
__global__ __launch_bounds__(256) void k_emit(const float* __restrict__ ThetaB,
                                              const float* __restrict__ E,
                                              const float* __restrict__ WA,
                                              unsigned char* __restrict__ btn8,
                                              float* __restrict__ partial,
                                              float* __restrict__ sumexp,
                                              float* __restrict__ A,
                                              unsigned* __restrict__ counter) {
    __shared__ float red[4][KT];
    __shared__ unsigned rank;
    int t    = threadIdx.x;
    int lane = t & 63;
    int w    = t >> 6;
    int n    = lane & 15;
    int q    = lane >> 4;
    int v0   = (blockIdx.x * 4 + w) * 16;

    // B-frags from E rows (cold HBM traffic — issue early): B[k=q*8+j][n=v]
    int rowE = v0 + n;
    bool valid = rowE < VV;
    rowE = valid ? rowE : VV - 1;
    float4 ex[4][2];
#pragma unroll
    for (int kt = 0; kt < 4; ++kt) {
        const float* p = E + (size_t)rowE * DD + kt * 32 + q * 8;
        ex[kt][0] = *(const float4*)p;
        ex[kt][1] = *(const float4*)(p + 4);
    }

    // A-frags from ThetaB: A[m=tag][k]: lane m=lane&15, k=q*8+j
    short8 Th[4][4];
#pragma unroll
    for (int kt = 0; kt < 4; ++kt)
#pragma unroll
        for (int mt = 0; mt < 4; ++mt) {
            const float* p = ThetaB + (mt * 16 + n) * DD + kt * 32 + q * 8;
            float4 x = *(const float4*)p;
            float4 y = *(const float4*)(p + 4);
            U8 f;
            f.u[0] = pk2(x.x, x.y); f.u[1] = pk2(x.z, x.w);
            f.u[2] = pk2(y.x, y.y); f.u[3] = pk2(y.z, y.w);
            Th[kt][mt] = f.v;
        }

    short8 Ef[4];
#pragma unroll
    for (int kt = 0; kt < 4; ++kt) {
        U8 f;
        f.u[0] = pk2(ex[kt][0].x, ex[kt][0].y); f.u[1] = pk2(ex[kt][0].z, ex[kt][0].w);
        f.u[2] = pk2(ex[kt][1].x, ex[kt][1].y); f.u[3] = pk2(ex[kt][1].z, ex[kt][1].w);
        Ef[kt] = f.v;
    }

#pragma unroll
    for (int mt = 0; mt < 4; ++mt) {
        f32x4 C = {0.f, 0.f, 0.f, 0.f};
#pragma unroll
        for (int kt = 0; kt < 4; ++kt)
            C = __builtin_amdgcn_mfma_f32_16x16x32_bf16(Th[kt][mt], Ef[kt], C, 0, 0, 0);
        // C[r]: tag t = mt*16 + q*4 + r, v-col = n
        float e[4];
#pragma unroll
        for (int r = 0; r < 4; ++r) e[r] = __expf(C[r]);
        if (valid) {
            // permuted byte position of tag t = 32h + 8qA + j: 16*qA + 8*h + j
            // for t = mt*16 + q*4 + r: qA=(2mt+(q>>1))&3, h=mt>>1, j=(q&1)*4+r
            int pos = 16 * ((2 * mt + (q >> 1)) & 3) + 8 * (mt >> 1) + (q & 1) * 4;
            *(unsigned*)(btn8 + (size_t)rowE * KT + pos) = pk4f8(e[0], e[1], e[2], e[3]);
        }
        // column sums: reduce over the 16 v-lanes (lane bits 0-3)
#pragma unroll
        for (int r = 0; r < 4; ++r) {
            float s = valid ? e[r] : 0.0f;
            s += __shfl_xor(s, 1, 64);
            s += __shfl_xor(s, 2, 64);
            s += __shfl_xor(s, 4, 64);
            s += __shfl_xor(s, 8, 64);
            if (n == 0) red[w][mt * 16 + q * 4 + r] = s;
        }
    }
    __syncthreads();
    if (w == 0) {
        float s = red[0][lane] + red[1][lane] + red[2][lane] + red[3][lane];
        partial[lane * PBLK + blockIdx.x] = s;
    }

    // ---- last-block-done: reduce partial -> sumexp, compute A (ex-k_sumA)
    __threadfence();                       // publish partial before arrival
    if (t == 0) rank = atomicAdd(counter, 1u);
    __syncthreads();
    if (rank == NBLK - 1) {
        __threadfence();                   // acquire other blocks' partials
        int k = t & 63, part = t >> 6;
        float s = 0.0f;
        for (int i = part; i < NBLK; i += 4) s += partial[k * PBLK + i];
        __syncthreads();                   // red[] free for reuse
        red[part][k] = s;
        __syncthreads();
        if (t < 64) sumexp[t] = red[0][t] + red[1][t] + red[2][t] + red[3][t];
        // A rows: wave w handles rows w*16 .. w*16+15 (full-wave softmax)
        for (int r = w * 16; r < w * 16 + 16; ++r) {
            float wv = WA[r * KT + lane];
            float e = (lane == BOS_T) ? 0.0f : __expf(wv);
            float se = e;
#pragma unroll
            for (int off = 32; off > 0; off >>= 1) se += __shfl_xor(se, off, 64);
            A[r * KT + lane] = e / se + EPSF;
        }
    }
}

// ---------------------------------------------------------------- forward scan: 4 waves/block, 3 producers + 1 consumer
__global__ __launch_bounds__(256) void k_fwd(const int* __restrict__ words,
                                             const unsigned char* __restrict__ btn8,
                                             const float* __restrict__ A,
                                             const float* __restrict__ sumexp,
                                             float* __restrict__ out) {
    __shared__ int shw[16 * LLEN];                                            // 8064 B
    __shared__ __attribute__((aligned(16))) unsigned char shE[2][TPH * 1024]; // 43008 B
    int lane = threadIdx.x & 63;
    int w    = threadIdx.x >> 6;   // waves 0-2: producers, wave 3: consumer
    int n    = lane & 15;          // sentence col (B/C side); row m (A side)
    int qA   = lane >> 4;
    int b0   = blockIdx.x * 16;

    // Stage word indices (contiguous 8064 B) cooperatively.
    {
        const uint4* src = (const uint4*)(words + (size_t)b0 * LLEN);
        uint4* dst = (uint4*)shw;
        for (int idx = threadIdx.x; idx < (16 * LLEN) / 4; idx += 256)
            dst[idx] = src[idx];
    }

    // Consumer-only state
    short8 Af[2][4];
    short8 B0, B1;
    if (w == 3) {
        // A-operand frags of scaled T'^T; tag at C-position (mt, m):
        //   tagn = 32*(mt>>1) + 8*(m>>2) + 4*(mt&1) + (m&3)
#pragma unroll
        for (int mt = 0; mt < 4; ++mt) {
            int tagn = 32 * (mt >> 1) + 8 * (n >> 2) + 4 * (mt & 1) + (n & 3);
            float s = sumexp[tagn];
            float rsn = (tagn == BOS_T || tagn == EOS_T) ? 0.0f : (SCALE_F / s);
#pragma unroll
            for (int kt = 0; kt < 2; ++kt) {
                U8 f;
#pragma unroll
                for (int j = 0; j < 8; ++j)
                    f.s[j] = f2bf(A[(kt * 32 + qA * 8 + j) * KT + tagn] * rsn);
                Af[kt][mt] = f.v;
            }
        }
        // beta_0 one-hot at tag 62 = B-position (kt=1, q=3, j=6)
        U8 z; z.u[0] = z.u[1] = z.u[2] = z.u[3] = 0;
        B0 = z.v;
        U8 o; o.u[0] = o.u[1] = o.u[2] = o.u[3] = 0;
        if (qA == 3) o.s[6] = (short)0x3F80;   // bf16(1.0)
        B1 = o.v;
    }
    __syncthreads();   // shw staged

    // producer staging of phase p_ into buffer bb: wave w takes steps w, w+3, ...
    // one GLLDS per step: 64 lanes x 16B = 16 sentences' permuted fp8 rows
#define PSTAGE(bb, p_)                                                        \
    do {                                                                      \
        for (int s_ = w; s_ < TPH; s_ += 3) {                                 \
            int wd_ = shw[n * LLEN + (p_) * TPH + s_];                        \
            const unsigned char* g_ = btn8 + (size_t)wd_ * KT + qA * 16;      \
            GLLDS(g_, &shE[bb][s_ * 1024]);                                   \
        }                                                                     \
        asm volatile("s_waitcnt vmcnt(0)" ::: "memory");                      \
    } while (0)

#define LDE(bb, ss) (*(const uint4*)(&shE[bb][(ss) * 1024] + lane * 16))

    if (w < 3) PSTAGE(0, 0);
    __syncthreads();   // phase 0 ready

    for (int p = 0; p < NPH; ++p) {
        int b = p & 1;
        if (w < 3) {
            if (p + 1 < NPH) PSTAGE((p + 1) & 1, p + 1);
        } else {
            // consumer: TPH steps from buffer b, no VMEM
            uint4 r0 = LDE(b, 0);
            uint4 r1 = LDE(b, 1);
#pragma unroll
            for (int s = 0; s < TPH; ++s) {
                uint4 rc = r0;
                r0 = r1;
                int s2 = (s + 2 < TPH) ? s + 2 : TPH - 1;
                r1 = LDE(b, s2);

                // decode 16 fp8 (prefetched 2 steps ago -> off the chain)
                f32x2 d0 = dec2lo(rc.x), d1 = dec2hi(rc.x);
                f32x2 d2 = dec2lo(rc.y), d3 = dec2hi(rc.y);
                f32x2 d4 = dec2lo(rc.z), d5 = dec2hi(rc.z);
                f32x2 d6 = dec2lo(rc.w), d7 = dec2hi(rc.w);

                // K-tiles as INDEPENDENT MFMAs + VALU add: one MFMA latency
                // on the chain instead of two (r13 change b)
                f32x4 C[4];
#pragma unroll
                for (int mt = 0; mt < 4; ++mt) {
                    f32x4 z4 = {0.f, 0.f, 0.f, 0.f};
                    f32x4 ca = __builtin_amdgcn_mfma_f32_16x16x32_bf16(Af[0][mt], B0, z4, 0, 0, 0);
                    f32x4 cb = __builtin_amdgcn_mfma_f32_16x16x32_bf16(Af[1][mt], B1, z4, 0, 0, 0);
                    C[mt] = ca + cb;
                }
                // next B-frags: kt slot j <- C[2kt+(j>>2)][j&3] * e_j  (in-lane)
                U8 f0, f1;
                f0.u[0] = pk2(C[0][0] * d0.x, C[0][1] * d0.y);
                f0.u[1] = pk2(C[0][2] * d1.x, C[0][3] * d1.y);
                f0.u[2] = pk2(C[1][0] * d2.x, C[1][1] * d2.y);
                f0.u[3] = pk2(C[1][2] * d3.x, C[1][3] * d3.y);
                f1.u[0] = pk2(C[2][0] * d4.x, C[2][1] * d4.y);
                f1.u[1] = pk2(C[2][2] * d5.x, C[2][3] * d5.y);
                f1.u[2] = pk2(C[3][0] * d6.x, C[3][1] * d6.y);
                f1.u[3] = pk2(C[3][2] * d7.x, C[3][3] * d7.y);
                B0 = f0.v; B1 = f1.v;
            }
        }
        __syncthreads();   // producers drained next phase; consumer done with b
    }

    // logZ = log(sum_k beta[k][n] * A[k][EOS]) - total scale
    if (w == 3) {
        short8 Afin[2];
#pragma unroll
        for (int kt = 0; kt < 2; ++kt) {
            U8 f;
#pragma unroll
            for (int j = 0; j < 8; ++j)
                f.s[j] = (n == 0) ? f2bf(A[(kt * 32 + qA * 8 + j) * KT + EOS_T]) : (short)0;
            Afin[kt] = f.v;
        }
        f32x4 Cf = {0.f, 0.f, 0.f, 0.f};
        Cf = __builtin_amdgcn_mfma_f32_16x16x32_bf16(Afin[0], B0, Cf, 0, 0, 0);
        Cf = __builtin_amdgcn_mfma_f32_16x16x32_bf16(Afin[1], B1, Cf, 0, 0, 0);
        if (qA == 0)
            out[b0 + n] = logf(Cf[0]) - LOG_TOTAL_SCALE;
    }
}

extern "C" void kernel_launch(void* const* d_in, const int* in_sizes, int n_in,
                              void* d_out, int out_size, void* d_ws, size_t ws_size,
                              hipStream_t stream) {
    const int*   words  = (const int*)d_in[0];     // [8192,126]
    const float* ThetaB = (const float*)d_in[1];   // [64,128]
    const float* WA     = (const float*)d_in[2];   // [64,64]
    const float* E      = (const float*)d_in[3];   // [50000,128]
    float* out = (float*)d_out;                    // [8192]

    char* ws = (char*)d_ws;
    unsigned char* btn8 = (unsigned char*)(ws + BTN_OFF);
    float* A        = (float*)(ws + A_OFF);
    float* sumexp   = (float*)(ws + SUM_OFF);
    float* partial  = (float*)(ws + PART_OFF);
    unsigned* counter = (unsigned*)(ws + CNT_OFF);

    hipMemsetAsync(counter, 0, 4, stream);   // graph-capturable memset node
    k_emit<<<NBLK, 256, 0, stream>>>(ThetaB, E, WA, btn8, partial, sumexp, A, counter);
    k_fwd<<<8192 / 16, 256, 0, stream>>>(words, btn8, A, sumexp, out);
}

// Round 14
// 143.240 us; speedup vs baseline: 1.8408x; 1.8408x over previous
//
#include <hip/hip_runtime.h>
#include <hip/hip_bf16.h>
#include <math.h>

// HMM forward (logZ), K=64 tags, V=50000, D=128, BATCH=8192, L=126.
// Transposed MFMA recurrence: beta_next = (T'^T x beta) .* e; C-layout ->
// next-B-layout transform by in-lane register renaming. Producer-consumer
// wave specialization; fp8 e4m3 emission table (3.2 MB, fits per-XCD L2),
// permuted rows, 1 global_load_lds per step.
// r14: (a) REVERTED r13's last-block fold — per-block __threadfence on
// non-coherent XCD L2s cost ~140us (782 serialized L2 writebacks); back to
// a separate k_sumA launch. (b) k_emit E-loads now staged through LDS with
// coalesced uint4 loads (r12's direct loads were 512 scattered 16B
// transactions per wave -> latency-bound, not HBM-bound).
//
// ws layout:
//   [0, 3,200,000)        btn8[v][64]   fp8e4m3  raw exp(logit), permuted order
//   [3,200,000, +16384)   A[i][j]       f32      softmax(WA, col BOS=-inf)+EPS
//   [3,216,384, +256)     sumexp[k]     f32
//   [3,216,640, +200704)  partial[k][784] f32    per-block column sums

#define KT 64
#define VV 50000
#define DD 128
#define BOS_T 62
#define EOS_T 63
#define LLEN 126
#define EPSF 1e-45f
#define SCALE_F 65536.0f
#define LOG_TOTAL_SCALE (2016.0f * 0.6931471805599453f)
#define NBLK 782          // k_emit grid (64 v-rows per block)
#define PBLK 784          // padded partial row
#define TPH 21            // k_fwd steps per phase (126 = 6*21)
#define NPH 6
#define EPITCH 132        // padded f32 row pitch of the E tile in LDS

#define BTN_OFF   0
#define A_OFF     3200000
#define SUM_OFF   3216384
#define PART_OFF  3216640

typedef short short8 __attribute__((ext_vector_type(8)));
typedef float f32x4  __attribute__((ext_vector_type(4)));
typedef float f32x2  __attribute__((ext_vector_type(2)));

union U8 { short8 v; unsigned u[4]; short s[8]; };

static __device__ inline unsigned short f2bf_u(float x) {
    __hip_bfloat16 h = __float2bfloat16(x);
    return *reinterpret_cast<unsigned short*>(&h);
}
static __device__ inline short f2bf(float x) { return (short)f2bf_u(x); }

#if __has_builtin(__builtin_amdgcn_cvt_pk_bf16_f32)
typedef __bf16 bf16x2 __attribute__((ext_vector_type(2)));
static __device__ inline unsigned pk2(float a, float b) {
    bf16x2 r = __builtin_amdgcn_cvt_pk_bf16_f32(a, b);
    return *reinterpret_cast<unsigned*>(&r);
}
#else
static __device__ inline unsigned pk2(float a, float b) {
    union { float f; unsigned u; } ua, ub;
    ua.f = a; ub.f = b;
    return ((ua.u + 0x8000u) >> 16) | ((ub.u + 0x8000u) & 0xFFFF0000u);
}
#endif

// ---- fp8 e4m3fn pack/unpack (values here are positive normals in [0.7,1.5])
#if __has_builtin(__builtin_amdgcn_cvt_pk_fp8_f32)
static __device__ inline unsigned pk4f8(float a, float b, float c, float d) {
    int v = __builtin_amdgcn_cvt_pk_fp8_f32(a, b, 0, false);
    v = __builtin_amdgcn_cvt_pk_fp8_f32(c, d, v, true);
    return (unsigned)v;
}
#else
static __device__ inline unsigned enc1f8(float x) {
    union { float f; unsigned u; } c; c.f = x;
    unsigned u = c.u & 0x7FFFFFFFu;
    unsigned r = u + 0x7FFFFu + ((u >> 20) & 1u);   // RNE to 3 mantissa bits
    return ((r >> 20) - (120u << 3)) & 0x7Fu;       // rebias 127->7
}
static __device__ inline unsigned pk4f8(float a, float b, float c, float d) {
    return enc1f8(a) | (enc1f8(b) << 8) | (enc1f8(c) << 16) | (enc1f8(d) << 24);
}
#endif

#if __has_builtin(__builtin_amdgcn_cvt_pk_f32_fp8)
static __device__ inline f32x2 dec2lo(unsigned w) { return __builtin_amdgcn_cvt_pk_f32_fp8((int)w, false); }
static __device__ inline f32x2 dec2hi(unsigned w) { return __builtin_amdgcn_cvt_pk_f32_fp8((int)w, true); }
#else
static __device__ inline float dec1f8(unsigned b) {
    union { unsigned u; float f; } c;
    c.u = ((b & 0x80u) << 24) | (((b & 0x7Fu) << 20) + (120u << 23));
    return c.f;
}
static __device__ inline f32x2 dec2lo(unsigned w) { f32x2 r; r.x = dec1f8(w & 0xFF); r.y = dec1f8((w >> 8) & 0xFF); return r; }
static __device__ inline f32x2 dec2hi(unsigned w) { f32x2 r; r.x = dec1f8((w >> 16) & 0xFF); r.y = dec1f8(w >> 24); return r; }
#endif

// async global(per-lane addr) -> LDS(uniform base + lane*16B), 16 B/lane
#if __has_builtin(__builtin_amdgcn_global_load_lds)
#define GLLDS(gp, lbase)                                                        \
    __builtin_amdgcn_global_load_lds(                                           \
        (__attribute__((address_space(1))) void*)const_cast<unsigned char*>(gp),\
        (__attribute__((address_space(3))) void*)(lbase), 16, 0, 0)
#else
#define GLLDS(gp, lbase)                                                        \
    do { *(uint4*)((unsigned char*)(lbase) + (threadIdx.x & 63) * 16) =         \
             *(const uint4*)(gp); } while (0)
#endif

// ---------------------------------------------------------------- btn8[v][pos(k)] = fp8(exp(ThetaB[k].E[v]))  (MFMA GEMM)
__global__ __launch_bounds__(256) void k_emit(const float* __restrict__ ThetaB,
                                              const float* __restrict__ E,
                                              unsigned char* __restrict__ btn8,
                                              float* __restrict__ partial) {
    __shared__ float tile[64 * EPITCH];   // 33792 B, 64 E-rows, padded pitch
    __shared__ float red[4][KT];
    int t    = threadIdx.x;
    int lane = t & 63;
    int w    = t >> 6;
    int n    = lane & 15;
    int q    = lane >> 4;
    int vblk = blockIdx.x * 64;
    int v0   = vblk + w * 16;

    // coalesced stage of 64 E-rows (32 KB): 2048 uint4, 256 threads x 8 iters
    {
        const float4* src = (const float4*)(E + (size_t)vblk * DD);
#pragma unroll
        for (int i = t; i < 64 * DD / 4; i += 256) {
            int row = i >> 5;            // 32 float4 per row
            int col = i & 31;
            float4 v = make_float4(0.f, 0.f, 0.f, 0.f);
            if (vblk + row < VV) v = src[i];
            *(float4*)&tile[row * EPITCH + col * 4] = v;
        }
    }

    // A-frags from ThetaB (32 KB, L2-resident): A[m=tag][k], m=lane&15, k=q*8+j
    short8 Th[4][4];
#pragma unroll
    for (int kt = 0; kt < 4; ++kt)
#pragma unroll
        for (int mt = 0; mt < 4; ++mt) {
            const float* p = ThetaB + (mt * 16 + n) * DD + kt * 32 + q * 8;
            float4 x = *(const float4*)p;
            float4 y = *(const float4*)(p + 4);
            U8 f;
            f.u[0] = pk2(x.x, x.y); f.u[1] = pk2(x.z, x.w);
            f.u[2] = pk2(y.x, y.y); f.u[3] = pk2(y.z, y.w);
            Th[kt][mt] = f.v;
        }
    __syncthreads();

    // B-frags from the LDS tile: B[k=q*8+j][n=v], local row w*16+n
    int rowE = v0 + n;
    bool valid = rowE < VV;
    short8 Ef[4];
#pragma unroll
    for (int kt = 0; kt < 4; ++kt) {
        const float* p = &tile[(w * 16 + n) * EPITCH + kt * 32 + q * 8];
        float4 x = *(const float4*)p;      // 2-way bank aliasing only (free)
        float4 y = *(const float4*)(p + 4);
        U8 f;
        f.u[0] = pk2(x.x, x.y); f.u[1] = pk2(x.z, x.w);
        f.u[2] = pk2(y.x, y.y); f.u[3] = pk2(y.z, y.w);
        Ef[kt] = f.v;
    }

#pragma unroll
    for (int mt = 0; mt < 4; ++mt) {
        f32x4 C = {0.f, 0.f, 0.f, 0.f};
#pragma unroll
        for (int kt = 0; kt < 4; ++kt)
            C = __builtin_amdgcn_mfma_f32_16x16x32_bf16(Th[kt][mt], Ef[kt], C, 0, 0, 0);
        // C[r]: tag tg = mt*16 + q*4 + r, v-col = n
        float e[4];
#pragma unroll
        for (int r = 0; r < 4; ++r) e[r] = __expf(C[r]);
        if (valid) {
            // permuted byte position of tag tg = 32h + 8qA + j: 16*qA + 8*h + j
            // for tg = mt*16 + q*4 + r: qA=(2mt+(q>>1))&3, h=mt>>1, j=(q&1)*4+r
            int pos = 16 * ((2 * mt + (q >> 1)) & 3) + 8 * (mt >> 1) + (q & 1) * 4;
            *(unsigned*)(btn8 + (size_t)rowE * KT + pos) = pk4f8(e[0], e[1], e[2], e[3]);
        }
        // column sums: reduce over the 16 v-lanes (lane bits 0-3)
#pragma unroll
        for (int r = 0; r < 4; ++r) {
            float s = valid ? e[r] : 0.0f;
            s += __shfl_xor(s, 1, 64);
            s += __shfl_xor(s, 2, 64);
            s += __shfl_xor(s, 4, 64);
            s += __shfl_xor(s, 8, 64);
            if (n == 0) red[w][mt * 16 + q * 4 + r] = s;
        }
    }
    __syncthreads();
    if (w == 0) {
        float s = red[0][lane] + red[1][lane] + red[2][lane] + red[3][lane];
        partial[lane * PBLK + blockIdx.x] = s;
    }
}

// ---------------------------------------------------------------- sumexp[k] = sum partial[k][:]; A row k = softmax(WA row k)
__global__ __launch_bounds__(256) void k_sumA(const float* __restrict__ partial,
                                              const float* __restrict__ WA,
                                              float* __restrict__ sumexp,
                                              float* __restrict__ A) {
    __shared__ float r[4];
    int k = blockIdx.x;
    int t = threadIdx.x;
    float s = 0.0f;
    for (int i = t; i < NBLK; i += 256) s += partial[k * PBLK + i];
#pragma unroll
    for (int off = 32; off > 0; off >>= 1) s += __shfl_xor(s, off, 64);
    if ((t & 63) == 0) r[t >> 6] = s;
    __syncthreads();
    if (t == 0) sumexp[k] = r[0] + r[1] + r[2] + r[3];
    if (t < 64) {
        float wv = WA[k * KT + t];
        float e = (t == BOS_T) ? 0.0f : __expf(wv);
        float se = e;
#pragma unroll
        for (int off = 32; off > 0; off >>= 1) se += __shfl_xor(se, off, 64);
        A[k * KT + t] = e / se + EPSF;
    }
}

// ---------------------------------------------------------------- forward scan: 4 waves/block, 3 producers + 1 consumer
__global__ __launch_bounds__(256) void k_fwd(const int* __restrict__ words,
                                             const unsigned char* __restrict__ btn8,
                                             const float* __restrict__ A,
                                             const float* __restrict__ sumexp,
                                             float* __restrict__ out) {
    __shared__ int shw[16 * LLEN];                                            // 8064 B
    __shared__ __attribute__((aligned(16))) unsigned char shE[2][TPH * 1024]; // 43008 B
    int lane = threadIdx.x & 63;
    int w    = threadIdx.x >> 6;   // waves 0-2: producers, wave 3: consumer
    int n    = lane & 15;          // sentence col (B/C side); row m (A side)
    int qA   = lane >> 4;
    int b0   = blockIdx.x * 16;

    // Stage word indices (contiguous 8064 B) cooperatively.
    {
        const uint4* src = (const uint4*)(words + (size_t)b0 * LLEN);
        uint4* dst = (uint4*)shw;
        for (int idx = threadIdx.x; idx < (16 * LLEN) / 4; idx += 256)
            dst[idx] = src[idx];
    }

    // Consumer-only state
    short8 Af[2][4];
    short8 B0, B1;
    if (w == 3) {
        // A-operand frags of scaled T'^T; tag at C-position (mt, m):
        //   tagn = 32*(mt>>1) + 8*(m>>2) + 4*(mt&1) + (m&3)
#pragma unroll
        for (int mt = 0; mt < 4; ++mt) {
            int tagn = 32 * (mt >> 1) + 8 * (n >> 2) + 4 * (mt & 1) + (n & 3);
            float s = sumexp[tagn];
            float rsn = (tagn == BOS_T || tagn == EOS_T) ? 0.0f : (SCALE_F / s);
#pragma unroll
            for (int kt = 0; kt < 2; ++kt) {
                U8 f;
#pragma unroll
                for (int j = 0; j < 8; ++j)
                    f.s[j] = f2bf(A[(kt * 32 + qA * 8 + j) * KT + tagn] * rsn);
                Af[kt][mt] = f.v;
            }
        }
        // beta_0 one-hot at tag 62 = B-position (kt=1, q=3, j=6)
        U8 z; z.u[0] = z.u[1] = z.u[2] = z.u[3] = 0;
        B0 = z.v;
        U8 o; o.u[0] = o.u[1] = o.u[2] = o.u[3] = 0;
        if (qA == 3) o.s[6] = (short)0x3F80;   // bf16(1.0)
        B1 = o.v;
    }
    __syncthreads();   // shw staged

    // producer staging of phase p_ into buffer bb: wave w takes steps w, w+3, ...
    // one GLLDS per step: 64 lanes x 16B = 16 sentences' permuted fp8 rows
#define PSTAGE(bb, p_)                                                        \
    do {                                                                      \
        for (int s_ = w; s_ < TPH; s_ += 3) {                                 \
            int wd_ = shw[n * LLEN + (p_) * TPH + s_];                        \
            const unsigned char* g_ = btn8 + (size_t)wd_ * KT + qA * 16;      \
            GLLDS(g_, &shE[bb][s_ * 1024]);                                   \
        }                                                                     \
        asm volatile("s_waitcnt vmcnt(0)" ::: "memory");                      \
    } while (0)

#define LDE(bb, ss) (*(const uint4*)(&shE[bb][(ss) * 1024] + lane * 16))

    if (w < 3) PSTAGE(0, 0);
    __syncthreads();   // phase 0 ready

    for (int p = 0; p < NPH; ++p) {
        int b = p & 1;
        if (w < 3) {
            if (p + 1 < NPH) PSTAGE((p + 1) & 1, p + 1);
        } else {
            // consumer: TPH steps from buffer b, no VMEM
            uint4 r0 = LDE(b, 0);
            uint4 r1 = LDE(b, 1);
#pragma unroll
            for (int s = 0; s < TPH; ++s) {
                uint4 rc = r0;
                r0 = r1;
                int s2 = (s + 2 < TPH) ? s + 2 : TPH - 1;
                r1 = LDE(b, s2);

                // decode 16 fp8 (prefetched 2 steps ago -> off the chain)
                f32x2 d0 = dec2lo(rc.x), d1 = dec2hi(rc.x);
                f32x2 d2 = dec2lo(rc.y), d3 = dec2hi(rc.y);
                f32x2 d4 = dec2lo(rc.z), d5 = dec2hi(rc.z);
                f32x2 d6 = dec2lo(rc.w), d7 = dec2hi(rc.w);

                // K-tiles as INDEPENDENT MFMAs + VALU add: one MFMA latency
                // on the chain instead of two
                f32x4 C[4];
#pragma unroll
                for (int mt = 0; mt < 4; ++mt) {
                    f32x4 z4 = {0.f, 0.f, 0.f, 0.f};
                    f32x4 ca = __builtin_amdgcn_mfma_f32_16x16x32_bf16(Af[0][mt], B0, z4, 0, 0, 0);
                    f32x4 cb = __builtin_amdgcn_mfma_f32_16x16x32_bf16(Af[1][mt], B1, z4, 0, 0, 0);
                    C[mt] = ca + cb;
                }
                // next B-frags: kt slot j <- C[2kt+(j>>2)][j&3] * e_j  (in-lane)
                U8 f0, f1;
                f0.u[0] = pk2(C[0][0] * d0.x, C[0][1] * d0.y);
                f0.u[1] = pk2(C[0][2] * d1.x, C[0][3] * d1.y);
                f0.u[2] = pk2(C[1][0] * d2.x, C[1][1] * d2.y);
                f0.u[3] = pk2(C[1][2] * d3.x, C[1][3] * d3.y);
                f1.u[0] = pk2(C[2][0] * d4.x, C[2][1] * d4.y);
                f1.u[1] = pk2(C[2][2] * d5.x, C[2][3] * d5.y);
                f1.u[2] = pk2(C[3][0] * d6.x, C[3][1] * d6.y);
                f1.u[3] = pk2(C[3][2] * d7.x, C[3][3] * d7.y);
                B0 = f0.v; B1 = f1.v;
            }
        }
        __syncthreads();   // producers drained next phase; consumer done with b
    }

    // logZ = log(sum_k beta[k][n] * A[k][EOS]) - total scale
    if (w == 3) {
        short8 Afin[2];
#pragma unroll
        for (int kt = 0; kt < 2; ++kt) {
            U8 f;
#pragma unroll
            for (int j = 0; j < 8; ++j)
                f.s[j] = (n == 0) ? f2bf(A[(kt * 32 + qA * 8 + j) * KT + EOS_T]) : (short)0;
            Afin[kt] = f.v;
        }
        f32x4 Cf = {0.f, 0.f, 0.f, 0.f};
        Cf = __builtin_amdgcn_mfma_f32_16x16x32_bf16(Afin[0], B0, Cf, 0, 0, 0);
        Cf = __builtin_amdgcn_mfma_f32_16x16x32_bf16(Afin[1], B1, Cf, 0, 0, 0);
        if (qA == 0)
            out[b0 + n] = logf(Cf[0]) - LOG_TOTAL_SCALE;
    }
}

extern "C" void kernel_launch(void* const* d_in, const int* in_sizes, int n_in,
                              void* d_out, int out_size, void* d_ws, size_t ws_size,
                              hipStream_t stream) {
    const int*   words  = (const int*)d_in[0];     // [8192,126]
    const float* ThetaB = (const float*)d_in[1];   // [64,128]
    const float* WA     = (const float*)d_in[2];   // [64,64]
    const float* E      = (const float*)d_in[3];   // [50000,128]
    float* out = (float*)d_out;                    // [8192]

    char* ws = (char*)d_ws;
    unsigned char* btn8 = (unsigned char*)(ws + BTN_OFF);
    float* A       = (float*)(ws + A_OFF);
    float* sumexp  = (float*)(ws + SUM_OFF);
    float* partial = (float*)(ws + PART_OFF);

    k_emit<<<NBLK, 256, 0, stream>>>(ThetaB, E, btn8, partial);
    k_sumA<<<KT, 256, 0, stream>>>(partial, WA, sumexp, A);
    k_fwd<<<8192 / 16, 256, 0, stream>>>(words, btn8, A, sumexp, out);
}